// Round 1
// baseline (2128.824 us; speedup 1.0000x reference)
//
#include <hip/hip_runtime.h>
#include <math.h>

#define N_PTS 131072
#define DIM   128
#define NBOOK 4
#define KCODES 1024

#define BM 64        // points per block
#define BK 64        // codes per LDS chunk
#define TM 4         // points per thread (stride 16)
#define TK 4         // codes per thread (stride 16)
#define LDS_PITCH (DIM + 4)   // 132 floats: 16B-aligned rows, %32 == 4 breaks bank aliasing

// ---------------- kernel 1: per-code squared norms ----------------
__global__ void csq_kernel(const float* __restrict__ cb, float* __restrict__ csq) {
    int idx = blockIdx.x * blockDim.x + threadIdx.x;   // 0 .. 4095 (b*K + k)
    const float4* p = (const float4*)(cb + (size_t)idx * DIM);
    float s = 0.f;
#pragma unroll
    for (int i = 0; i < DIM / 4; ++i) {
        float4 v = p[i];
        s += v.x * v.x + v.y * v.y + v.z * v.z + v.w * v.w;
    }
    csq[idx] = s;
}

// ---------------- kernel 2: fused dot + argmin ----------------
__global__ __launch_bounds__(256)
void argmin_kernel(const float* __restrict__ x,
                   const float* __restrict__ cb,
                   const float* __restrict__ csq,
                   int* __restrict__ out) {
    __shared__ float xs[BM][LDS_PITCH];
    __shared__ float cs[BK][LDS_PITCH];
    __shared__ float cq[BK];

    const int b   = blockIdx.y;
    const int n0  = blockIdx.x * BM;
    const int tid = threadIdx.x;
    const int tx  = tid & 15;    // code group
    const int ty  = tid >> 4;    // point group

    // ---- stage x tile: 64 points x 128 dims, coalesced float4 ----
    {
        const float4* xg = (const float4*)(x + (size_t)n0 * DIM);
#pragma unroll
        for (int i = 0; i < (BM * DIM / 4) / 256; ++i) {   // 8 iters
            int flat = i * 256 + tid;
            int p  = flat >> 5;        // point 0..63
            int d4 = flat & 31;        // float4 index within row
            float4 v = xg[p * (DIM / 4) + d4];
            *(float4*)&xs[p][d4 * 4] = v;
        }
    }

    float bestd[TM];
    int   besti[TM];
#pragma unroll
    for (int p = 0; p < TM; ++p) { bestd[p] = 3.4e38f; besti[p] = 0; }

    const float* cbb = cb + (size_t)b * KCODES * DIM;

    for (int kc = 0; kc < KCODES; kc += BK) {
        __syncthreads();
        // ---- stage code chunk ----
        const float4* cg = (const float4*)(cbb + (size_t)kc * DIM);
#pragma unroll
        for (int i = 0; i < (BK * DIM / 4) / 256; ++i) {   // 8 iters
            int flat = i * 256 + tid;
            int p  = flat >> 5;
            int d4 = flat & 31;
            float4 v = cg[p * (DIM / 4) + d4];
            *(float4*)&cs[p][d4 * 4] = v;
        }
        if (tid < BK) cq[tid] = csq[b * KCODES + kc + tid];
        __syncthreads();

        float acc[TM][TK];
#pragma unroll
        for (int p = 0; p < TM; ++p)
#pragma unroll
            for (int c = 0; c < TK; ++c) acc[p][c] = 0.f;

#pragma unroll 4
        for (int d = 0; d < DIM; d += 4) {
            float4 xa[TM], ca[TK];
#pragma unroll
            for (int p = 0; p < TM; ++p)
                xa[p] = *(const float4*)&xs[ty + 16 * p][d];
#pragma unroll
            for (int c = 0; c < TK; ++c)
                ca[c] = *(const float4*)&cs[tx + 16 * c][d];
#pragma unroll
            for (int p = 0; p < TM; ++p)
#pragma unroll
                for (int c = 0; c < TK; ++c) {
                    acc[p][c] += xa[p].x * ca[c].x;
                    acc[p][c] += xa[p].y * ca[c].y;
                    acc[p][c] += xa[p].z * ca[c].z;
                    acc[p][c] += xa[p].w * ca[c].w;
                }
        }

        // ---- fused argmin epilogue for this chunk ----
#pragma unroll
        for (int c = 0; c < TK; ++c) {
            int klocal = tx + 16 * c;
            int kglob  = kc + klocal;
            float cqv  = cq[klocal];
#pragma unroll
            for (int p = 0; p < TM; ++p) {
                float dist = cqv - 2.f * acc[p][c];
                // strict < plus index tie-break == numpy first-min
                if (dist < bestd[p] || (dist == bestd[p] && kglob < besti[p])) {
                    bestd[p] = dist;
                    besti[p] = kglob;
                }
            }
        }
    }

    // ---- reduce across the 16 tx lanes (xor masks 1..8 stay in 16-lane groups) ----
#pragma unroll
    for (int p = 0; p < TM; ++p) {
        float bd = bestd[p];
        int   bi = besti[p];
#pragma unroll
        for (int off = 8; off > 0; off >>= 1) {
            float od = __shfl_xor(bd, off);
            int   oi = __shfl_xor(bi, off);
            if (od < bd || (od == bd && oi < bi)) { bd = od; bi = oi; }
        }
        if (tx == 0) {
            int n = n0 + ty + 16 * p;
            out[(size_t)n * NBOOK + b] = bi;
        }
    }
}

extern "C" void kernel_launch(void* const* d_in, const int* in_sizes, int n_in,
                              void* d_out, int out_size, void* d_ws, size_t ws_size,
                              hipStream_t stream) {
    const float* x  = (const float*)d_in[0];        // [N, D] fp32
    const float* cb = (const float*)d_in[1];        // [B, K, D] fp32
    int* out = (int*)d_out;                         // [N, B] int32
    float* csq = (float*)d_ws;                      // [B*K] fp32 scratch

    csq_kernel<<<dim3((NBOOK * KCODES) / 256), dim3(256), 0, stream>>>(cb, csq);

    dim3 grid(N_PTS / BM, NBOOK);
    argmin_kernel<<<grid, dim3(256), 0, stream>>>(x, cb, csq, out);
}

// Round 2
// 678.941 us; speedup vs baseline: 3.1355x; 3.1355x over previous
//
#include <hip/hip_runtime.h>
#include <math.h>

#define N_PTS  131072
#define DIM    128
#define NBOOK  4
#define KCODES 1024

#define CHUNK     64          // codes per LDS chunk
#define NCHUNK    (KCODES / CHUNK)       // 16
#define WPTS      32          // points per wave
#define BPTS      128         // points per block (4 waves)
#define EPS       0.05f
#define WL_CAP    131072

typedef short  bf16x8 __attribute__((ext_vector_type(8)));
typedef float  f32x4  __attribute__((ext_vector_type(4)));
typedef unsigned short u16;

// ws layout:
//   [0, 2MB)            cb_frag  (4 books x 16 chunks x 32 slots x 64 lanes x 8 bf16)
//   [2MB, +16KB)        csq      (4096 fp32)
//   [2MB+16KB, +4B)     counter
//   [2MB+16KB+256, ..)  worklist (131072 int)
#define WS_CSQ_OFF  (2u << 20)
#define WS_CNT_OFF  ((2u << 20) + 16384u)
#define WS_WL_OFF   ((2u << 20) + 16384u + 256u)

// round-to-nearest-even fp32 -> bf16 split (hi + residual-lo)
__device__ inline void split2(float v, u16& hb_out, u16& lb_out) {
    unsigned u = __float_as_uint(v);
    unsigned hb = (u + 0x7fffu + ((u >> 16) & 1u)) >> 16;
    hb_out = (u16)hb;
    float hv = __uint_as_float(hb << 16);
    float lo = v - hv;                       // exact (Sterbenz)
    unsigned u2 = __float_as_uint(lo);
    unsigned lb = (u2 + 0x7fffu + ((u2 >> 16) & 1u)) >> 16;
    lb_out = (u16)lb;
}

__device__ inline void async_copy16(const void* g, void* l) {
    __builtin_amdgcn_global_load_lds(
        (const __attribute__((address_space(1))) void*)g,
        (__attribute__((address_space(3))) void*)l,
        16, 0, 0);
}

// ---------------- prep: zero the worklist counter ----------------
__global__ void zero_kernel(int* __restrict__ counter) {
    if (threadIdx.x == 0) *counter = 0;
}

// ---------------- prep: per-code squared norms (fp32 exact) ----------------
__global__ void csq_kernel(const float* __restrict__ cb, float* __restrict__ csq) {
    int idx = blockIdx.x * blockDim.x + threadIdx.x;   // 0 .. 4095
    const float4* p = (const float4*)(cb + (size_t)idx * DIM);
    float s = 0.f;
#pragma unroll
    for (int i = 0; i < DIM / 4; ++i) {
        float4 v = p[i];
        s += v.x * v.x + v.y * v.y + v.z * v.z + v.w * v.w;
    }
    csq[idx] = s;
}

// ---------------- prep: codebook -> fragment-ordered bf16 hi/lo ----------------
// layout: [b][chunk(16)][slot(32)=(ct*4+s)*2+h][lane(64)][8 bf16]
// frag semantics: lane l of (ct,s,h): code = chunk*64+ct*16+(l&15),
//                 dims = s*32 + (l>>4)*8 .. +7
__global__ void cbfrag_kernel(const float* __restrict__ cb, u16* __restrict__ cbf) {
    int t    = blockIdx.x * blockDim.x + threadIdx.x;  // 0 .. 131071
    int lane = t & 63;
    int slot = (t >> 6) & 31;
    int c    = (t >> 11) & 15;
    int b    = t >> 15;
    int h  = slot & 1;
    int s  = (slot >> 1) & 3;
    int ct = slot >> 3;
    int code = c * CHUNK + ct * 16 + (lane & 15);
    int d0   = s * 32 + (lane >> 4) * 8;
    const float* row = cb + (((size_t)b * KCODES + code) * DIM + d0);
    u16 o[8];
#pragma unroll
    for (int j = 0; j < 8; ++j) {
        u16 hb, lb;
        split2(row[j], hb, lb);
        o[j] = h ? lb : hb;
    }
    u16* dst = cbf + (size_t)t * 8;
#pragma unroll
    for (int j = 0; j < 8; ++j) dst[j] = o[j];
}

// ---------------- main: MFMA dot + fused argmin + margin flag ----------------
__global__ __launch_bounds__(256, 3)
void argmin_mfma_kernel(const float* __restrict__ x,
                        const u16*  __restrict__ cbf,
                        const float* __restrict__ csq,
                        int* __restrict__ out,
                        int* __restrict__ counter,
                        int* __restrict__ worklist) {
    __shared__ u16 lds[CHUNK * DIM * 2];   // 32 KB: one chunk, hi+lo, frag order

    const int tid  = threadIdx.x;
    const int lane = tid & 63;
    const int w    = tid >> 6;
    const int b    = blockIdx.y;
    const int n0   = blockIdx.x * BPTS;
    const int lm   = lane & 15;
    const int Q    = lane >> 4;

    // ---- A fragments: this wave's 32 points, hi+lo, all 4 d-steps, in regs ----
    bf16x8 ah[2][4], al[2][4];
#pragma unroll
    for (int mt = 0; mt < 2; ++mt) {
        const float* xrow = x + (size_t)(n0 + w * WPTS + mt * 16 + lm) * DIM;
#pragma unroll
        for (int s = 0; s < 4; ++s) {
            const float* p = xrow + s * 32 + Q * 8;
            bf16x8 hv, lv;
#pragma unroll
            for (int j = 0; j < 8; ++j) {
                u16 hb, lb;
                split2(p[j], hb, lb);
                hv[j] = (short)hb;
                lv[j] = (short)lb;
            }
            ah[mt][s] = hv;
            al[mt][s] = lv;
        }
    }

    float bestd[2][4], best2[2][4];
    int   besti[2][4];
#pragma unroll
    for (int mt = 0; mt < 2; ++mt)
#pragma unroll
        for (int r = 0; r < 4; ++r) {
            bestd[mt][r] = 3.4e38f;
            best2[mt][r] = 3.4e38f;
            besti[mt][r] = 0;
        }

    const u16* cbb = cbf + (size_t)b * NCHUNK * (CHUNK * DIM * 2);
    const float* csqb = csq + b * KCODES;

    for (int c = 0; c < NCHUNK; ++c) {
        if (c) __syncthreads();            // all waves done reading prev chunk
        // ---- stage 32 KB chunk: 8 issues x (256 threads x 16 B) ----
        const u16* src = cbb + (size_t)c * (CHUNK * DIM * 2);
#pragma unroll
        for (int i = 0; i < 8; ++i) {
            // per-lane global addr; LDS base wave-uniform (+ implicit lane*16)
            async_copy16(src + i * 2048 + tid * 8, &lds[i * 2048 + w * 512]);
        }
        // prefetch csq for this chunk (hides L2 latency behind the barrier)
        float cq[4];
#pragma unroll
        for (int ct = 0; ct < 4; ++ct)
            cq[ct] = csqb[c * CHUNK + ct * 16 + lm];
        __syncthreads();                   // staging visible

        f32x4 acc[2][4];
#pragma unroll
        for (int mt = 0; mt < 2; ++mt)
#pragma unroll
            for (int ct = 0; ct < 4; ++ct)
                acc[mt][ct] = (f32x4){0.f, 0.f, 0.f, 0.f};

#pragma unroll
        for (int s = 0; s < 4; ++s) {
            bf16x8 bh[4], bl[4];
#pragma unroll
            for (int ct = 0; ct < 4; ++ct) {
                int slot = (ct * 4 + s) * 2;
                bh[ct] = *(const bf16x8*)&lds[slot * 512 + lane * 8];
                bl[ct] = *(const bf16x8*)&lds[(slot + 1) * 512 + lane * 8];
            }
#pragma unroll
            for (int mt = 0; mt < 2; ++mt)
#pragma unroll
                for (int ct = 0; ct < 4; ++ct) {
                    acc[mt][ct] = __builtin_amdgcn_mfma_f32_16x16x32_bf16(ah[mt][s], bh[ct], acc[mt][ct], 0, 0, 0);
                    acc[mt][ct] = __builtin_amdgcn_mfma_f32_16x16x32_bf16(ah[mt][s], bl[ct], acc[mt][ct], 0, 0, 0);
                    acc[mt][ct] = __builtin_amdgcn_mfma_f32_16x16x32_bf16(al[mt][s], bh[ct], acc[mt][ct], 0, 0, 0);
                }
        }

        // ---- fused argmin + second-best (codes ascend: strict < = first-min) ----
#pragma unroll
        for (int ct = 0; ct < 4; ++ct) {
            int code = c * CHUNK + ct * 16 + lm;
#pragma unroll
            for (int mt = 0; mt < 2; ++mt)
#pragma unroll
                for (int r = 0; r < 4; ++r) {
                    float d = cq[ct] - 2.f * acc[mt][ct][r];
                    if (d < bestd[mt][r]) {
                        best2[mt][r] = bestd[mt][r];
                        bestd[mt][r] = d;
                        besti[mt][r] = code;
                    } else if (d < best2[mt][r]) {
                        best2[mt][r] = d;
                    }
                }
        }
    }

    // ---- cross-lane merge over the 16 code-lanes of each quad ----
#pragma unroll
    for (int mt = 0; mt < 2; ++mt)
#pragma unroll
        for (int r = 0; r < 4; ++r) {
            float bd = bestd[mt][r], b2 = best2[mt][r];
            int   bi = besti[mt][r];
#pragma unroll
            for (int off = 1; off < 16; off <<= 1) {
                float od = __shfl_xor(bd, off);
                float o2 = __shfl_xor(b2, off);
                int   oi = __shfl_xor(bi, off);
                float nb2 = fminf(fminf(b2, o2), fmaxf(bd, od));
                if (od < bd || (od == bd && oi < bi)) { bd = od; bi = oi; }
                b2 = nb2;
            }
            if (lm == 0) {
                int point = n0 + w * WPTS + mt * 16 + Q * 4 + r;
                out[point * NBOOK + b] = bi;
                if (b2 - bd < EPS) {
                    int pos = atomicAdd(counter, 1);
                    if (pos < WL_CAP) worklist[pos] = point * NBOOK + b;
                }
            }
        }
}

// ---------------- fallback: exact fp32 recompute for small-margin items ----------------
__global__ __launch_bounds__(256)
void exact_kernel(const float* __restrict__ x,
                  const float* __restrict__ cb,
                  const float* __restrict__ csq,
                  const int* __restrict__ counter,
                  const int* __restrict__ worklist,
                  int* __restrict__ out) {
    __shared__ float xs[DIM];
    __shared__ float rbest[4];
    __shared__ int   ribest[4];

    int nitems = *counter;
    if (nitems > WL_CAP) nitems = WL_CAP;

    for (int item = blockIdx.x; item < nitems; item += gridDim.x) {
        int nb = worklist[item];
        int n = nb >> 2, b = nb & 3;
        __syncthreads();
        if (threadIdx.x < 32) {
            float4 v = ((const float4*)(x + (size_t)n * DIM))[threadIdx.x];
            *(float4*)&xs[threadIdx.x * 4] = v;
        }
        __syncthreads();

        const float* cbb = cb + (size_t)b * KCODES * DIM;
        float bd = 3.4e38f;
        int   bi = 0;
#pragma unroll
        for (int kk = 0; kk < 4; ++kk) {
            int k = threadIdx.x * 4 + kk;          // ascending within thread
            const float* crow = cbb + (size_t)k * DIM;
            float dot = 0.f;
#pragma unroll 8
            for (int d = 0; d < DIM; d += 4) {
                float4 cv = *(const float4*)(crow + d);
                dot += xs[d] * cv.x + xs[d + 1] * cv.y + xs[d + 2] * cv.z + xs[d + 3] * cv.w;
            }
            float dist = csq[b * KCODES + k] - 2.f * dot;
            if (dist < bd) { bd = dist; bi = k; }
        }
        // wave-level merge with index tie-break
        for (int off = 1; off < 64; off <<= 1) {
            float od = __shfl_xor(bd, off);
            int   oi = __shfl_xor(bi, off);
            if (od < bd || (od == bd && oi < bi)) { bd = od; bi = oi; }
        }
        int w = threadIdx.x >> 6;
        if ((threadIdx.x & 63) == 0) { rbest[w] = bd; ribest[w] = bi; }
        __syncthreads();
        if (threadIdx.x == 0) {
            float fb = rbest[0]; int fi = ribest[0];
            for (int i = 1; i < 4; ++i) {
                if (rbest[i] < fb || (rbest[i] == fb && ribest[i] < fi)) {
                    fb = rbest[i]; fi = ribest[i];
                }
            }
            out[nb] = fi;
        }
    }
}

extern "C" void kernel_launch(void* const* d_in, const int* in_sizes, int n_in,
                              void* d_out, int out_size, void* d_ws, size_t ws_size,
                              hipStream_t stream) {
    const float* x  = (const float*)d_in[0];   // [N, D] fp32
    const float* cb = (const float*)d_in[1];   // [B, K, D] fp32
    int* out = (int*)d_out;                    // [N, B] int32

    char* ws = (char*)d_ws;
    u16*   cbf      = (u16*)ws;
    float* csq      = (float*)(ws + WS_CSQ_OFF);
    int*   counter  = (int*)(ws + WS_CNT_OFF);
    int*   worklist = (int*)(ws + WS_WL_OFF);

    zero_kernel<<<1, 64, 0, stream>>>(counter);
    csq_kernel<<<(NBOOK * KCODES) / 256, 256, 0, stream>>>(cb, csq);
    cbfrag_kernel<<<(NBOOK * NCHUNK * 32 * 64) / 256, 256, 0, stream>>>(cb, cbf);

    dim3 grid(N_PTS / BPTS, NBOOK);
    argmin_mfma_kernel<<<grid, 256, 0, stream>>>(x, cbf, csq, out, counter, worklist);

    exact_kernel<<<256, 256, 0, stream>>>(x, cb, csq, counter, worklist, out);
}

// Round 3
// 639.050 us; speedup vs baseline: 3.3312x; 1.0624x over previous
//
#include <hip/hip_runtime.h>
#include <math.h>

#define N_PTS  131072
#define DIM    128
#define NBOOK  4
#define KCODES 1024

#define CHUNK     64                     // codes per LDS chunk
#define NCHUNK    (KCODES / CHUNK)       // 16
#define WPTS      32                     // points per wave
#define BPTS      128                    // points per block (4 waves)
#define EPS       0.02f                  // 12x the ~1.6e-3 6-sigma split-bf16 error
#define WL_CAP    131072

typedef short  bf16x8 __attribute__((ext_vector_type(8)));
typedef float  f32x4  __attribute__((ext_vector_type(4)));
typedef unsigned short u16;

// ws layout:
//   [0, 2MB)            cb_frag  (4 books x 16 chunks x 32 slots x 64 lanes x 8 bf16)
//   [2MB, +16KB)        csq      (4096 fp32)
//   [2MB+16KB, +4B)     counter
//   [2MB+16KB+256, ..)  worklist (131072 int)
#define WS_CSQ_OFF  (2u << 20)
#define WS_CNT_OFF  ((2u << 20) + 16384u)
#define WS_WL_OFF   ((2u << 20) + 16384u + 256u)

// round-to-nearest-even fp32 -> bf16 split (hi + residual-lo)
__device__ inline void split2(float v, u16& hb_out, u16& lb_out) {
    unsigned u = __float_as_uint(v);
    unsigned hb = (u + 0x7fffu + ((u >> 16) & 1u)) >> 16;
    hb_out = (u16)hb;
    float hv = __uint_as_float(hb << 16);
    float lo = v - hv;                       // exact (Sterbenz)
    unsigned u2 = __float_as_uint(lo);
    unsigned lb = (u2 + 0x7fffu + ((u2 >> 16) & 1u)) >> 16;
    lb_out = (u16)lb;
}

__device__ inline void async_copy16(const void* g, void* l) {
    __builtin_amdgcn_global_load_lds(
        (const __attribute__((address_space(1))) void*)g,
        (__attribute__((address_space(3))) void*)l,
        16, 0, 0);
}

// ---------------- fused prep: cbfrag (blocks 0..511) + csq/zero (512..527) ----------------
// cbf layout: [b][chunk(16)][slot(32)=(ct*4+s)*2+h][lane(64)][8 bf16]
// frag semantics: lane l of (ct,s,h): code = chunk*64+ct*16+(l&15), dims = s*32+(l>>4)*8 ..+7
__global__ __launch_bounds__(256)
void prep_kernel(const float* __restrict__ cb, u16* __restrict__ cbf,
                 float* __restrict__ csq, int* __restrict__ counter) {
    if (blockIdx.x >= 512) {
        int idx = (blockIdx.x - 512) * 256 + threadIdx.x;   // 0..4095
        if (idx == 0) *counter = 0;
        const float4* p = (const float4*)(cb + (size_t)idx * DIM);
        float s = 0.f;
#pragma unroll
        for (int i = 0; i < DIM / 4; ++i) {
            float4 v = p[i];
            s += v.x * v.x + v.y * v.y + v.z * v.z + v.w * v.w;
        }
        csq[idx] = s;
        return;
    }
    int t    = blockIdx.x * 256 + threadIdx.x;  // 0 .. 131071
    int lane = t & 63;
    int slot = (t >> 6) & 31;
    int c    = (t >> 11) & 15;
    int b    = t >> 15;
    int h  = slot & 1;
    int s  = (slot >> 1) & 3;
    int ct = slot >> 3;
    int code = c * CHUNK + ct * 16 + (lane & 15);
    int d0   = s * 32 + (lane >> 4) * 8;
    const float* row = cb + (((size_t)b * KCODES + code) * DIM + d0);
    float4 v0 = *(const float4*)row;
    float4 v1 = *(const float4*)(row + 4);
    float vals[8] = {v0.x, v0.y, v0.z, v0.w, v1.x, v1.y, v1.z, v1.w};
    u16 o[8];
#pragma unroll
    for (int j = 0; j < 8; ++j) {
        u16 hb, lb;
        split2(vals[j], hb, lb);
        o[j] = h ? lb : hb;
    }
    u16* dst = cbf + (size_t)t * 8;
#pragma unroll
    for (int j = 0; j < 8; ++j) dst[j] = o[j];
}

// ---------------- main: MFMA dot + fused argmin + margin flag, all 4 books ----------------
__global__ __launch_bounds__(256, 4)
void argmin_mfma_kernel(const float* __restrict__ x,
                        const u16*  __restrict__ cbf,
                        const float* __restrict__ csq,
                        int* __restrict__ out,
                        int* __restrict__ counter,
                        int* __restrict__ worklist) {
    __shared__ u16 lds[CHUNK * DIM * 2];   // 32 KB: one chunk, hi+lo, frag order

    const int tid  = threadIdx.x;
    const int lane = tid & 63;
    const int w    = tid >> 6;
    const int n0   = blockIdx.x * BPTS;
    const int lm   = lane & 15;
    const int Q    = lane >> 4;

    // ---- A fragments: this wave's 32 points, hi+lo, all 4 d-steps, in regs ----
    bf16x8 ah[2][4], al[2][4];
#pragma unroll
    for (int mt = 0; mt < 2; ++mt) {
        const float* xrow = x + (size_t)(n0 + w * WPTS + mt * 16 + lm) * DIM;
#pragma unroll
        for (int s = 0; s < 4; ++s) {
            const float* p = xrow + s * 32 + Q * 8;
            float4 v0 = *(const float4*)p;
            float4 v1 = *(const float4*)(p + 4);
            float vals[8] = {v0.x, v0.y, v0.z, v0.w, v1.x, v1.y, v1.z, v1.w};
            bf16x8 hv, lv;
#pragma unroll
            for (int j = 0; j < 8; ++j) {
                u16 hb, lb;
                split2(vals[j], hb, lb);
                hv[j] = (short)hb;
                lv[j] = (short)lb;
            }
            ah[mt][s] = hv;
            al[mt][s] = lv;
        }
    }

    for (int b = 0; b < NBOOK; ++b) {
        float bestd[2][4], best2[2][4];
        int   besti[2][4];
#pragma unroll
        for (int mt = 0; mt < 2; ++mt)
#pragma unroll
            for (int r = 0; r < 4; ++r) {
                bestd[mt][r] = 3.4e38f;
                best2[mt][r] = 3.4e38f;
                besti[mt][r] = 0;
            }

        const u16* cbb = cbf + (size_t)b * NCHUNK * (CHUNK * DIM * 2);
        const float* csqb = csq + b * KCODES;

        for (int c = 0; c < NCHUNK; ++c) {
            __syncthreads();               // all waves done reading prev chunk
            // ---- stage 32 KB chunk: 8 issues x (256 threads x 16 B) ----
            const u16* src = cbb + (size_t)c * (CHUNK * DIM * 2);
#pragma unroll
            for (int i = 0; i < 8; ++i) {
                async_copy16(src + i * 2048 + tid * 8, &lds[i * 2048 + w * 512]);
            }
            float cq[4];
#pragma unroll
            for (int ct = 0; ct < 4; ++ct)
                cq[ct] = csqb[c * CHUNK + ct * 16 + lm];
            __syncthreads();               // staging visible

            f32x4 acc[2][4];
#pragma unroll
            for (int mt = 0; mt < 2; ++mt)
#pragma unroll
                for (int ct = 0; ct < 4; ++ct)
                    acc[mt][ct] = (f32x4){0.f, 0.f, 0.f, 0.f};

#pragma unroll
            for (int s = 0; s < 4; ++s) {
                bf16x8 bh[4], bl[4];
#pragma unroll
                for (int ct = 0; ct < 4; ++ct) {
                    int slot = (ct * 4 + s) * 2;
                    bh[ct] = *(const bf16x8*)&lds[slot * 512 + lane * 8];
                    bl[ct] = *(const bf16x8*)&lds[(slot + 1) * 512 + lane * 8];
                }
#pragma unroll
                for (int mt = 0; mt < 2; ++mt)
#pragma unroll
                    for (int ct = 0; ct < 4; ++ct) {
                        acc[mt][ct] = __builtin_amdgcn_mfma_f32_16x16x32_bf16(ah[mt][s], bh[ct], acc[mt][ct], 0, 0, 0);
                        acc[mt][ct] = __builtin_amdgcn_mfma_f32_16x16x32_bf16(ah[mt][s], bl[ct], acc[mt][ct], 0, 0, 0);
                        acc[mt][ct] = __builtin_amdgcn_mfma_f32_16x16x32_bf16(al[mt][s], bh[ct], acc[mt][ct], 0, 0, 0);
                    }
            }

            // ---- fused argmin + second-best (codes ascend: strict < = first-min) ----
#pragma unroll
            for (int ct = 0; ct < 4; ++ct) {
                int code = c * CHUNK + ct * 16 + lm;
#pragma unroll
                for (int mt = 0; mt < 2; ++mt)
#pragma unroll
                    for (int r = 0; r < 4; ++r) {
                        float d = cq[ct] - 2.f * acc[mt][ct][r];
                        if (d < bestd[mt][r]) {
                            best2[mt][r] = bestd[mt][r];
                            bestd[mt][r] = d;
                            besti[mt][r] = code;
                        } else if (d < best2[mt][r]) {
                            best2[mt][r] = d;
                        }
                    }
            }
        }

        // ---- cross-lane merge over the 16 code-lanes of each quad ----
#pragma unroll
        for (int mt = 0; mt < 2; ++mt)
#pragma unroll
            for (int r = 0; r < 4; ++r) {
                float bd = bestd[mt][r], b2 = best2[mt][r];
                int   bi = besti[mt][r];
#pragma unroll
                for (int off = 1; off < 16; off <<= 1) {
                    float od = __shfl_xor(bd, off);
                    float o2 = __shfl_xor(b2, off);
                    int   oi = __shfl_xor(bi, off);
                    float nb2 = fminf(fminf(b2, o2), fmaxf(bd, od));
                    if (od < bd || (od == bd && oi < bi)) { bd = od; bi = oi; }
                    b2 = nb2;
                }
                if (lm == 0) {
                    int point = n0 + w * WPTS + mt * 16 + Q * 4 + r;
                    out[point * NBOOK + b] = bi;
                    if (b2 - bd < EPS) {
                        int pos = atomicAdd(counter, 1);
                        if (pos < WL_CAP) worklist[pos] = point * NBOOK + b;
                    }
                }
            }
    }
}

// ---------------- fallback: exact fp32 recompute for small-margin items ----------------
__global__ __launch_bounds__(256)
void exact_kernel(const float* __restrict__ x,
                  const float* __restrict__ cb,
                  const float* __restrict__ csq,
                  const int* __restrict__ counter,
                  const int* __restrict__ worklist,
                  int* __restrict__ out) {
    __shared__ float xs[DIM];
    __shared__ float rbest[4];
    __shared__ int   ribest[4];

    int nitems = *counter;
    if (nitems > WL_CAP) nitems = WL_CAP;

    for (int item = blockIdx.x; item < nitems; item += gridDim.x) {
        int nb = worklist[item];
        int n = nb >> 2, b = nb & 3;
        __syncthreads();
        if (threadIdx.x < 32) {
            float4 v = ((const float4*)(x + (size_t)n * DIM))[threadIdx.x];
            *(float4*)&xs[threadIdx.x * 4] = v;
        }
        __syncthreads();

        const float* cbb = cb + (size_t)b * KCODES * DIM;
        // 4 codes per thread: k = kk*256 + tid (ascending within thread)
        const float* crow[4];
#pragma unroll
        for (int kk = 0; kk < 4; ++kk)
            crow[kk] = cbb + (size_t)(kk * 256 + threadIdx.x) * DIM;

        float dots[4] = {0.f, 0.f, 0.f, 0.f};
#pragma unroll 8
        for (int d = 0; d < DIM; d += 4) {
            float4 xv = *(const float4*)&xs[d];
#pragma unroll
            for (int kk = 0; kk < 4; ++kk) {
                float4 cv = *(const float4*)(crow[kk] + d);
                dots[kk] += xv.x * cv.x + xv.y * cv.y + xv.z * cv.z + xv.w * cv.w;
            }
        }

        float bd = 3.4e38f;
        int   bi = 0;
#pragma unroll
        for (int kk = 0; kk < 4; ++kk) {
            int k = kk * 256 + threadIdx.x;
            float dist = csq[b * KCODES + k] - 2.f * dots[kk];
            if (dist < bd) { bd = dist; bi = k; }
        }
        // wave-level merge with index tie-break
        for (int off = 1; off < 64; off <<= 1) {
            float od = __shfl_xor(bd, off);
            int   oi = __shfl_xor(bi, off);
            if (od < bd || (od == bd && oi < bi)) { bd = od; bi = oi; }
        }
        int w = threadIdx.x >> 6;
        if ((threadIdx.x & 63) == 0) { rbest[w] = bd; ribest[w] = bi; }
        __syncthreads();
        if (threadIdx.x == 0) {
            float fb = rbest[0]; int fi = ribest[0];
            for (int i = 1; i < 4; ++i) {
                if (rbest[i] < fb || (rbest[i] == fb && ribest[i] < fi)) {
                    fb = rbest[i]; fi = ribest[i];
                }
            }
            out[nb] = fi;
        }
    }
}

extern "C" void kernel_launch(void* const* d_in, const int* in_sizes, int n_in,
                              void* d_out, int out_size, void* d_ws, size_t ws_size,
                              hipStream_t stream) {
    const float* x  = (const float*)d_in[0];   // [N, D] fp32
    const float* cb = (const float*)d_in[1];   // [B, K, D] fp32
    int* out = (int*)d_out;                    // [N, B] int32

    char* ws = (char*)d_ws;
    u16*   cbf      = (u16*)ws;
    float* csq      = (float*)(ws + WS_CSQ_OFF);
    int*   counter  = (int*)(ws + WS_CNT_OFF);
    int*   worklist = (int*)(ws + WS_WL_OFF);

    prep_kernel<<<528, 256, 0, stream>>>(cb, cbf, csq, counter);

    argmin_mfma_kernel<<<N_PTS / BPTS, 256, 0, stream>>>(x, cbf, csq, out, counter, worklist);

    exact_kernel<<<512, 256, 0, stream>>>(x, cb, csq, counter, worklist, out);
}

// Round 4
// 494.407 us; speedup vs baseline: 4.3058x; 1.2926x over previous
//
#include <hip/hip_runtime.h>
#include <math.h>

#define N_PTS  131072
#define DIM    128
#define NBOOK  4
#define KCODES 1024

#define CHUNK   64                   // codes per LDS chunk
#define NCHUNK  16
#define PT      2                    // point tiles (32 pts each) per wave -> 64 pts/wave
#define BPTS    256                  // 4 waves * 64 points
#define SLOTS   34                   // 2 ct * (8 s * 2 hl + 1 csq)
#define CHUNK_BYTES (SLOTS * 1024)   // 34816 B
#define EPS_ACC 2.5e-3f              // margin in acc units (~5e-3 in distance units)
#define WL_CAP  131072

typedef short  bf16x8 __attribute__((ext_vector_type(8)));
typedef float  f32x16 __attribute__((ext_vector_type(16)));
typedef unsigned short u16;

// ws layout: cbf (4*16*34816 = 2228224 B) | csq fp32[4096] | counter | worklist
#define WS_CSQ_OFF  2359296u
#define WS_CNT_OFF  (WS_CSQ_OFF + 16384u)
#define WS_WL_OFF   (WS_CNT_OFF + 256u)

__device__ inline u16 bf16_rne(float v) {
    unsigned u = __float_as_uint(v);
    return (u16)((u + 0x7fffu + ((u >> 16) & 1u)) >> 16);
}
__device__ inline float bf16_up(u16 h) { return __uint_as_float(((unsigned)h) << 16); }

// fp32 -> bf16 hi + bf16 residual-lo
__device__ inline void split2(float v, u16& hb, u16& lb) {
    hb = bf16_rne(v);
    lb = bf16_rne(v - bf16_up(hb));
}

__device__ inline void async_copy16(const void* g, void* l) {
    __builtin_amdgcn_global_load_lds(
        (const __attribute__((address_space(1))) void*)g,
        (__attribute__((address_space(3))) void*)l,
        16, 0, 0);
}

// ---------------- prep: codebook -> A-fragment bf16 (32x32x16 layout) + csq + counter ----
// cbf: [b][chunk][slot(34)][lane(64)][8 bf16];  slot = ct*17 + (s*2+h | 16=csq)
// A-frag: row(code-in-tile) = lane&31, k = (lane>>5)*8 + j
__global__ __launch_bounds__(256)
void prep_kernel(const float* __restrict__ cb, u16* __restrict__ cbf,
                 float* __restrict__ csq, int* __restrict__ counter) {
    if (blockIdx.x >= 544) {                       // csq + counter blocks
        int idx = (blockIdx.x - 544) * 256 + threadIdx.x;   // 0..4095
        if (idx == 0) *counter = 0;
        const float4* p = (const float4*)(cb + (size_t)idx * DIM);
        float s = 0.f;
#pragma unroll
        for (int i = 0; i < DIM / 4; ++i) {
            float4 v = p[i];
            s += v.x * v.x + v.y * v.y + v.z * v.z + v.w * v.w;
        }
        csq[idx] = s;
        return;
    }
    int t    = blockIdx.x * 256 + threadIdx.x;     // 0 .. 139263
    int lane = t & 63;
    int slotIdx = t >> 6;
    int slot = slotIdx % SLOTS;
    int bc   = slotIdx / SLOTS;                    // 0..63
    int chunk = bc & 15;
    int b     = bc >> 4;
    int ct = (slot >= 17) ? 1 : 0;
    int sl = slot - ct * 17;

    u16 o[8] = {0, 0, 0, 0, 0, 0, 0, 0};
    if (sl < 16) {
        int s = sl >> 1, h = sl & 1;
        int code = chunk * CHUNK + ct * 32 + (lane & 31);
        int d0   = s * 16 + (lane >> 5) * 8;
        const float* row = cb + ((size_t)b * KCODES + code) * DIM + d0;
        float4 v0 = *(const float4*)row;
        float4 v1 = *(const float4*)(row + 4);
        float vals[8] = {v0.x, v0.y, v0.z, v0.w, v1.x, v1.y, v1.z, v1.w};
#pragma unroll
        for (int j = 0; j < 8; ++j) {
            u16 hb, lb;
            split2(vals[j], hb, lb);
            o[j] = h ? lb : hb;
        }
    } else if (lane < 32) {                        // csq slice: k=0 hi, k=1 mid, k=2 r2
        int code = chunk * CHUNK + ct * 32 + lane;
        const float4* p = (const float4*)(cb + ((size_t)b * KCODES + code) * DIM);
        float ssum = 0.f;
#pragma unroll
        for (int i = 0; i < DIM / 4; ++i) {
            float4 v = p[i];
            ssum += v.x * v.x + v.y * v.y + v.z * v.z + v.w * v.w;
        }
        u16 hb = bf16_rne(ssum);
        float rem1 = ssum - bf16_up(hb);
        u16 mb = bf16_rne(rem1);
        u16 rb = bf16_rne(rem1 - bf16_up(mb));
        o[0] = hb; o[1] = mb; o[2] = rb;
    }
    u16* dst = cbf + (size_t)t * 8;
#pragma unroll
    for (int j = 0; j < 8; ++j) dst[j] = o[j];
}

// ---------------- main: 32x32x16 MFMA, codes=A(LDS), points=B(regs), packed argmax ----
__global__ __launch_bounds__(256, 2)
void argmin_mfma_kernel(const float* __restrict__ x,
                        const u16*  __restrict__ cbf,
                        int* __restrict__ out,
                        int* __restrict__ counter,
                        int* __restrict__ worklist) {
    __shared__ u16 lds[SLOTS * 512];               // 34816 B

    const int tid  = threadIdx.x;
    const int lane = tid & 63;
    const int w    = tid >> 6;
    const int n0   = blockIdx.x * BPTS;
    const int col  = lane & 31;
    const int kh   = lane >> 5;

    // ---- B fragments (points), hi+lo, all 8 s-steps, in regs: 128 VGPRs ----
    bf16x8 xh[PT][8], xl[PT][8];
#pragma unroll
    for (int pt = 0; pt < PT; ++pt) {
        const float* xrow = x + (size_t)(n0 + w * 64 + pt * 32 + col) * DIM;
#pragma unroll
        for (int s = 0; s < 8; ++s) {
            const float* p = xrow + s * 16 + kh * 8;
            float4 v0 = *(const float4*)p;
            float4 v1 = *(const float4*)(p + 4);
            float vals[8] = {v0.x, v0.y, v0.z, v0.w, v1.x, v1.y, v1.z, v1.w};
            bf16x8 hv, lv;
#pragma unroll
            for (int j = 0; j < 8; ++j) {
                u16 hb, lb;
                split2(vals[j], hb, lb);
                hv[j] = (short)hb;
                lv[j] = (short)lb;
            }
            xh[pt][s] = hv;
            xl[pt][s] = lv;
        }
    }
    // csq-slice B frag: -0.5 at k=0,1,2 (lanes<32), else 0
    bf16x8 xcf;
#pragma unroll
    for (int j = 0; j < 8; ++j)
        xcf[j] = (kh == 0 && j < 3) ? (short)0xBF00 : (short)0;

    for (int b = 0; b < NBOOK; ++b) {
        unsigned b1p[PT], b2p[PT];
        int bchunk[PT];
#pragma unroll
        for (int pt = 0; pt < PT; ++pt) { b1p[pt] = 0u; b2p[pt] = 0u; bchunk[pt] = 0; }

        const char* cbb = (const char*)cbf + (size_t)b * NCHUNK * CHUNK_BYTES;

        for (int c = 0; c < NCHUNK; ++c) {
            __syncthreads();                       // prev chunk fully consumed
            const char* src = cbb + (size_t)c * CHUNK_BYTES;
            char* ldsb = (char*)lds;
#pragma unroll
            for (int i = 0; i < 8; ++i)
                async_copy16(src + i * 4096 + tid * 16, ldsb + i * 4096 + w * 1024);
            if (tid < 128)
                async_copy16(src + 8 * 4096 + tid * 16, ldsb + 8 * 4096 + w * 1024);
            __syncthreads();                       // staging visible

            f32x16 acc[2][PT];                     // [ct][pt]
#pragma unroll
            for (int ct = 0; ct < 2; ++ct)
#pragma unroll
                for (int pt = 0; pt < PT; ++pt)
#pragma unroll
                    for (int r = 0; r < 16; ++r) acc[ct][pt][r] = 0.f;

#pragma unroll
            for (int s = 0; s < 8; ++s) {
                bf16x8 a0h = *(const bf16x8*)&lds[(0 * 17 + s * 2) * 512 + lane * 8];
                bf16x8 a0l = *(const bf16x8*)&lds[(0 * 17 + s * 2 + 1) * 512 + lane * 8];
                bf16x8 a1h = *(const bf16x8*)&lds[(1 * 17 + s * 2) * 512 + lane * 8];
                bf16x8 a1l = *(const bf16x8*)&lds[(1 * 17 + s * 2 + 1) * 512 + lane * 8];
#pragma unroll
                for (int pt = 0; pt < PT; ++pt) {
                    acc[0][pt] = __builtin_amdgcn_mfma_f32_32x32x16_bf16(a0h, xh[pt][s], acc[0][pt], 0, 0, 0);
                    acc[0][pt] = __builtin_amdgcn_mfma_f32_32x32x16_bf16(a0h, xl[pt][s], acc[0][pt], 0, 0, 0);
                    acc[0][pt] = __builtin_amdgcn_mfma_f32_32x32x16_bf16(a0l, xh[pt][s], acc[0][pt], 0, 0, 0);
                    acc[1][pt] = __builtin_amdgcn_mfma_f32_32x32x16_bf16(a1h, xh[pt][s], acc[1][pt], 0, 0, 0);
                    acc[1][pt] = __builtin_amdgcn_mfma_f32_32x32x16_bf16(a1h, xl[pt][s], acc[1][pt], 0, 0, 0);
                    acc[1][pt] = __builtin_amdgcn_mfma_f32_32x32x16_bf16(a1l, xh[pt][s], acc[1][pt], 0, 0, 0);
                }
            }
            {   // csq slice (hi-only data x const -0.5 frag)
                bf16x8 a0c = *(const bf16x8*)&lds[16 * 512 + lane * 8];
                bf16x8 a1c = *(const bf16x8*)&lds[(17 + 16) * 512 + lane * 8];
#pragma unroll
                for (int pt = 0; pt < PT; ++pt) {
                    acc[0][pt] = __builtin_amdgcn_mfma_f32_32x32x16_bf16(a0c, xcf, acc[0][pt], 0, 0, 0);
                    acc[1][pt] = __builtin_amdgcn_mfma_f32_32x32x16_bf16(a1c, xcf, acc[1][pt], 0, 0, 0);
                }
            }

            // ---- packed top-2 argmax epilogue: acc = dot - csq/2, larger = nearer ----
#pragma unroll
            for (int pt = 0; pt < PT; ++pt) {
                unsigned prev = b1p[pt];
                unsigned p1 = prev, p2 = b2p[pt];
#pragma unroll
                for (int ct = 0; ct < 2; ++ct)
#pragma unroll
                    for (int r = 0; r < 16; ++r) {
                        float sv = acc[ct][pt][r] + 192.0f;     // positive, < 256
                        unsigned leaf = (unsigned)(ct * 16 + r); // ascending code order
                        unsigned pk = (__float_as_uint(sv) & 0xFFFFFFE0u) | (31u - leaf);
                        unsigned lo = pk < p1 ? pk : p1;        // min
                        p2 = p2 > lo ? p2 : lo;                 // max
                        p1 = p1 > pk ? p1 : pk;                 // max
                    }
                bchunk[pt] = (p1 != prev) ? c : bchunk[pt];
                b1p[pt] = p1; b2p[pt] = p2;
            }
        }

        // ---- decode, cross-half merge, write ----
#pragma unroll
        for (int pt = 0; pt < PT; ++pt) {
            unsigned leaf = 31u - (b1p[pt] & 31u);
            float m1 = __uint_as_float(b1p[pt] & 0xFFFFFFE0u) - 192.0f;
            float m2 = __uint_as_float(b2p[pt] & 0xFFFFFFE0u) - 192.0f;
            int r = (int)(leaf & 15u), ct = (int)(leaf >> 4);
            int row = (r & 3) + 8 * (r >> 2) + 4 * kh;
            int code = bchunk[pt] * CHUNK + ct * 32 + row;

            float om1 = __shfl_xor(m1, 32);
            float om2 = __shfl_xor(m2, 32);
            int   oc  = __shfl_xor(code, 32);
            bool take = (om1 > m1) || (om1 == m1 && oc < code);
            float nm2 = fmaxf(fminf(m1, om1), fmaxf(m2, om2));
            if (take) { m1 = om1; code = oc; }
            m2 = nm2;

            if (lane < 32) {
                int point = n0 + w * 64 + pt * 32 + col;
                out[point * NBOOK + b] = code;
                if (m1 - m2 < EPS_ACC) {
                    int pos = atomicAdd(counter, 1);
                    if (pos < WL_CAP) worklist[pos] = point * NBOOK + b;
                }
            }
        }
    }
}

// ---------------- fallback: exact fp32 recompute for small-margin items ----------------
__global__ __launch_bounds__(256)
void exact_kernel(const float* __restrict__ x,
                  const float* __restrict__ cb,
                  const float* __restrict__ csq,
                  const int* __restrict__ counter,
                  const int* __restrict__ worklist,
                  int* __restrict__ out) {
    __shared__ float xs[DIM];
    __shared__ float rbest[4];
    __shared__ int   ribest[4];

    int nitems = *counter;
    if (nitems > WL_CAP) nitems = WL_CAP;

    for (int item = blockIdx.x; item < nitems; item += gridDim.x) {
        int nb = worklist[item];
        int n = nb >> 2, b = nb & 3;
        __syncthreads();
        if (threadIdx.x < 32) {
            float4 v = ((const float4*)(x + (size_t)n * DIM))[threadIdx.x];
            *(float4*)&xs[threadIdx.x * 4] = v;
        }
        __syncthreads();

        const float* cbb = cb + (size_t)b * KCODES * DIM;
        const float* crow[4];
#pragma unroll
        for (int kk = 0; kk < 4; ++kk)
            crow[kk] = cbb + (size_t)(kk * 256 + threadIdx.x) * DIM;

        float dots[4] = {0.f, 0.f, 0.f, 0.f};
#pragma unroll 8
        for (int d = 0; d < DIM; d += 4) {
            float4 xv = *(const float4*)&xs[d];
#pragma unroll
            for (int kk = 0; kk < 4; ++kk) {
                float4 cv = *(const float4*)(crow[kk] + d);
                dots[kk] += xv.x * cv.x + xv.y * cv.y + xv.z * cv.z + xv.w * cv.w;
            }
        }

        float bd = 3.4e38f;
        int   bi = 0;
#pragma unroll
        for (int kk = 0; kk < 4; ++kk) {
            int k = kk * 256 + threadIdx.x;
            float dist = csq[b * KCODES + k] - 2.f * dots[kk];
            if (dist < bd) { bd = dist; bi = k; }
        }
        for (int off = 1; off < 64; off <<= 1) {
            float od = __shfl_xor(bd, off);
            int   oi = __shfl_xor(bi, off);
            if (od < bd || (od == bd && oi < bi)) { bd = od; bi = oi; }
        }
        int w = threadIdx.x >> 6;
        if ((threadIdx.x & 63) == 0) { rbest[w] = bd; ribest[w] = bi; }
        __syncthreads();
        if (threadIdx.x == 0) {
            float fb = rbest[0]; int fi = ribest[0];
            for (int i = 1; i < 4; ++i) {
                if (rbest[i] < fb || (rbest[i] == fb && ribest[i] < fi)) {
                    fb = rbest[i]; fi = ribest[i];
                }
            }
            out[nb] = fi;
        }
    }
}

extern "C" void kernel_launch(void* const* d_in, const int* in_sizes, int n_in,
                              void* d_out, int out_size, void* d_ws, size_t ws_size,
                              hipStream_t stream) {
    const float* x  = (const float*)d_in[0];   // [N, D] fp32
    const float* cb = (const float*)d_in[1];   // [B, K, D] fp32
    int* out = (int*)d_out;                    // [N, B] int32

    char* ws = (char*)d_ws;
    u16*   cbf      = (u16*)ws;
    float* csq      = (float*)(ws + WS_CSQ_OFF);
    int*   counter  = (int*)(ws + WS_CNT_OFF);
    int*   worklist = (int*)(ws + WS_WL_OFF);

    prep_kernel<<<560, 256, 0, stream>>>(cb, cbf, csq, counter);

    argmin_mfma_kernel<<<N_PTS / BPTS, 256, 0, stream>>>(x, cbf, out, counter, worklist);

    exact_kernel<<<512, 256, 0, stream>>>(x, cb, csq, counter, worklist, out);
}

// Round 5
// 457.741 us; speedup vs baseline: 4.6507x; 1.0801x over previous
//
#include <hip/hip_runtime.h>
#include <math.h>

#define N_PTS  131072
#define DIM    128
#define NBOOK  4
#define KCODES 1024

#define CHUNK   64                   // codes per LDS chunk
#define NCHUNK  16
#define PT      2                    // point tiles (32 pts each) per wave -> 64 pts/wave
#define BPTS    256                  // 4 waves * 64 points
#define SLOTS   34                   // 2 ct * (8 s * 2 hl + 1 csq)
#define CHUNK_BYTES (SLOTS * 1024)   // 34816 B
#define EPS_ACC 2.5e-3f              // margin in acc units (~5e-3 in distance units)
#define WL_CAP  131072

typedef short  bf16x8 __attribute__((ext_vector_type(8)));
typedef float  f32x16 __attribute__((ext_vector_type(16)));
typedef unsigned short u16;

// ws layout: cbf (4*16*34816 = 2228224 B) | csq fp32[4096] | counter | worklist
#define WS_CSQ_OFF  2359296u
#define WS_CNT_OFF  (WS_CSQ_OFF + 16384u)
#define WS_WL_OFF   (WS_CNT_OFF + 256u)

__device__ inline u16 bf16_rne(float v) {
    unsigned u = __float_as_uint(v);
    return (u16)((u + 0x7fffu + ((u >> 16) & 1u)) >> 16);
}
__device__ inline float bf16_up(u16 h) { return __uint_as_float(((unsigned)h) << 16); }

// fp32 -> bf16 hi + bf16 residual-lo
__device__ inline void split2(float v, u16& hb, u16& lb) {
    hb = bf16_rne(v);
    lb = bf16_rne(v - bf16_up(hb));
}

__device__ inline void async_copy16(const void* g, void* l) {
    __builtin_amdgcn_global_load_lds(
        (const __attribute__((address_space(1))) void*)g,
        (__attribute__((address_space(3))) void*)l,
        16, 0, 0);
}

// ---------------- prep: codebook -> A-fragment bf16 (32x32x16 layout) + csq + counter ----
// cbf: [b][chunk][slot(34)][lane(64)][8 bf16];  slot = ct*17 + (s*2+h | 16=csq)
// A-frag: row(code-in-tile) = lane&31, k = (lane>>5)*8 + j
// csq slot per row: k0=csq_hi, k1=csq_mid, k2=csq_r2 (x -0.5), k3=320 (x 1.0 bias)
__global__ __launch_bounds__(256)
void prep_kernel(const float* __restrict__ cb, u16* __restrict__ cbf,
                 float* __restrict__ csq, int* __restrict__ counter) {
    if (blockIdx.x >= 544) {                       // csq + counter blocks
        int idx = (blockIdx.x - 544) * 256 + threadIdx.x;   // 0..4095
        if (idx == 0) *counter = 0;
        const float4* p = (const float4*)(cb + (size_t)idx * DIM);
        float s = 0.f;
#pragma unroll
        for (int i = 0; i < DIM / 4; ++i) {
            float4 v = p[i];
            s += v.x * v.x + v.y * v.y + v.z * v.z + v.w * v.w;
        }
        csq[idx] = s;
        return;
    }
    int t    = blockIdx.x * 256 + threadIdx.x;     // 0 .. 139263
    int lane = t & 63;
    int slotIdx = t >> 6;
    int slot = slotIdx % SLOTS;
    int bc   = slotIdx / SLOTS;                    // 0..63
    int chunk = bc & 15;
    int b     = bc >> 4;
    int ct = (slot >= 17) ? 1 : 0;
    int sl = slot - ct * 17;

    u16 o[8] = {0, 0, 0, 0, 0, 0, 0, 0};
    if (sl < 16) {
        int s = sl >> 1, h = sl & 1;
        int code = chunk * CHUNK + ct * 32 + (lane & 31);
        int d0   = s * 16 + (lane >> 5) * 8;
        const float* row = cb + ((size_t)b * KCODES + code) * DIM + d0;
        float4 v0 = *(const float4*)row;
        float4 v1 = *(const float4*)(row + 4);
        float vals[8] = {v0.x, v0.y, v0.z, v0.w, v1.x, v1.y, v1.z, v1.w};
#pragma unroll
        for (int j = 0; j < 8; ++j) {
            u16 hb, lb;
            split2(vals[j], hb, lb);
            o[j] = h ? lb : hb;
        }
    } else if (lane < 32) {                        // csq slice
        int code = chunk * CHUNK + ct * 32 + lane;
        const float4* p = (const float4*)(cb + ((size_t)b * KCODES + code) * DIM);
        float ssum = 0.f;
#pragma unroll
        for (int i = 0; i < DIM / 4; ++i) {
            float4 v = p[i];
            ssum += v.x * v.x + v.y * v.y + v.z * v.z + v.w * v.w;
        }
        u16 hb = bf16_rne(ssum);
        float rem1 = ssum - bf16_up(hb);
        u16 mb = bf16_rne(rem1);
        u16 rb = bf16_rne(rem1 - bf16_up(mb));
        o[0] = hb; o[1] = mb; o[2] = rb;
        o[3] = (u16)0x43A0;                        // 320.0 bias (x 1.0 in B)
    }
    u16* dst = cbf + (size_t)t * 8;
#pragma unroll
    for (int j = 0; j < 8; ++j) dst[j] = o[j];
}

// ---------------- main: 32x32x16 MFMA, codes=A(LDS), points=B(regs), packed argmax ----
// grid: (512, 2); block y handles books {2y, 2y+1} -> 1024 blocks, 4 blocks/CU
__global__ __launch_bounds__(256, 2)
void argmin_mfma_kernel(const float* __restrict__ x,
                        const u16*  __restrict__ cbf,
                        int* __restrict__ out,
                        int* __restrict__ counter,
                        int* __restrict__ worklist) {
    __shared__ u16 lds[SLOTS * 512];               // 34816 B

    const int tid  = threadIdx.x;
    const int lane = tid & 63;
    const int w    = tid >> 6;
    const int n0   = blockIdx.x * BPTS;
    const int col  = lane & 31;
    const int kh   = lane >> 5;

    // ---- B fragments (points), hi+lo, all 8 s-steps, in regs ----
    bf16x8 xh[PT][8], xl[PT][8];
#pragma unroll
    for (int pt = 0; pt < PT; ++pt) {
        const float* xrow = x + (size_t)(n0 + w * 64 + pt * 32 + col) * DIM;
#pragma unroll
        for (int s = 0; s < 8; ++s) {
            const float* p = xrow + s * 16 + kh * 8;
            float4 v0 = *(const float4*)p;
            float4 v1 = *(const float4*)(p + 4);
            float vals[8] = {v0.x, v0.y, v0.z, v0.w, v1.x, v1.y, v1.z, v1.w};
            bf16x8 hv, lv;
#pragma unroll
            for (int j = 0; j < 8; ++j) {
                u16 hb, lb;
                split2(vals[j], hb, lb);
                hv[j] = (short)hb;
                lv[j] = (short)lb;
            }
            xh[pt][s] = hv;
            xl[pt][s] = lv;
        }
    }
    // csq-slice B frag: k0..k2 = -0.5 (csq terms), k3 = 1.0 (bias term)
    bf16x8 xcf;
#pragma unroll
    for (int j = 0; j < 8; ++j) {
        short v = 0;
        if (kh == 0) {
            if (j < 3) v = (short)0xBF00;          // -0.5
            else if (j == 3) v = (short)0x3F80;    // 1.0
        }
        xcf[j] = v;
    }

    for (int bb = 0; bb < 2; ++bb) {
        const int b = blockIdx.y * 2 + bb;
        unsigned b1p[PT], b2p[PT];
        int bchunk[PT];
#pragma unroll
        for (int pt = 0; pt < PT; ++pt) { b1p[pt] = 0u; b2p[pt] = 0u; bchunk[pt] = 0; }

        const char* cbb = (const char*)cbf + (size_t)b * NCHUNK * CHUNK_BYTES;

        for (int c = 0; c < NCHUNK; ++c) {
            __syncthreads();                       // prev chunk fully consumed
            const char* src = cbb + (size_t)c * CHUNK_BYTES;
            char* ldsb = (char*)lds;
#pragma unroll
            for (int i = 0; i < 8; ++i)
                async_copy16(src + i * 4096 + tid * 16, ldsb + i * 4096 + w * 1024);
            if (tid < 128)
                async_copy16(src + 8 * 4096 + tid * 16, ldsb + 8 * 4096 + w * 1024);
            __syncthreads();                       // staging visible

            f32x16 acc[2][PT];                     // [ct][pt]
#pragma unroll
            for (int ct = 0; ct < 2; ++ct)
#pragma unroll
                for (int pt = 0; pt < PT; ++pt)
#pragma unroll
                    for (int r = 0; r < 16; ++r) acc[ct][pt][r] = 0.f;

#pragma unroll
            for (int s = 0; s < 8; ++s) {
                bf16x8 a0h = *(const bf16x8*)&lds[(0 * 17 + s * 2) * 512 + lane * 8];
                bf16x8 a0l = *(const bf16x8*)&lds[(0 * 17 + s * 2 + 1) * 512 + lane * 8];
                bf16x8 a1h = *(const bf16x8*)&lds[(1 * 17 + s * 2) * 512 + lane * 8];
                bf16x8 a1l = *(const bf16x8*)&lds[(1 * 17 + s * 2 + 1) * 512 + lane * 8];
#pragma unroll
                for (int pt = 0; pt < PT; ++pt) {
                    acc[0][pt] = __builtin_amdgcn_mfma_f32_32x32x16_bf16(a0h, xh[pt][s], acc[0][pt], 0, 0, 0);
                    acc[0][pt] = __builtin_amdgcn_mfma_f32_32x32x16_bf16(a0h, xl[pt][s], acc[0][pt], 0, 0, 0);
                    acc[0][pt] = __builtin_amdgcn_mfma_f32_32x32x16_bf16(a0l, xh[pt][s], acc[0][pt], 0, 0, 0);
                    acc[1][pt] = __builtin_amdgcn_mfma_f32_32x32x16_bf16(a1h, xh[pt][s], acc[1][pt], 0, 0, 0);
                    acc[1][pt] = __builtin_amdgcn_mfma_f32_32x32x16_bf16(a1h, xl[pt][s], acc[1][pt], 0, 0, 0);
                    acc[1][pt] = __builtin_amdgcn_mfma_f32_32x32x16_bf16(a1l, xh[pt][s], acc[1][pt], 0, 0, 0);
                }
            }
            {   // csq + bias slice: acc = dot - csq/2 + 320  (positive -> bits monotone)
                bf16x8 a0c = *(const bf16x8*)&lds[16 * 512 + lane * 8];
                bf16x8 a1c = *(const bf16x8*)&lds[(17 + 16) * 512 + lane * 8];
#pragma unroll
                for (int pt = 0; pt < PT; ++pt) {
                    acc[0][pt] = __builtin_amdgcn_mfma_f32_32x32x16_bf16(a0c, xcf, acc[0][pt], 0, 0, 0);
                    acc[1][pt] = __builtin_amdgcn_mfma_f32_32x32x16_bf16(a1c, xcf, acc[1][pt], 0, 0, 0);
                }
            }

            // ---- packed top-2 argmax epilogue (pair-merged; larger = nearer) ----
#pragma unroll
            for (int pt = 0; pt < PT; ++pt) {
                unsigned prev = b1p[pt];
                unsigned p1 = prev, p2 = b2p[pt];
#pragma unroll
                for (int ct = 0; ct < 2; ++ct)
#pragma unroll
                    for (int r = 0; r < 16; r += 2) {
                        unsigned la = (unsigned)(ct * 16 + r);
                        unsigned pa = (__float_as_uint(acc[ct][pt][r])     & 0xFFFFFFE0u) | (31u - la);
                        unsigned pb = (__float_as_uint(acc[ct][pt][r + 1]) & 0xFFFFFFE0u) | (30u - la);
                        unsigned hi = pa > pb ? pa : pb;
                        unsigned lo = pa < pb ? pa : pb;
                        unsigned t  = hi < p1 ? hi : p1;
                        unsigned m  = lo > t ? lo : t;
                        p2 = p2 > m ? p2 : m;                 // -> v_max3
                        p1 = p1 > hi ? p1 : hi;
                    }
                bchunk[pt] = (p1 != prev) ? c : bchunk[pt];
                b1p[pt] = p1; b2p[pt] = p2;
            }
        }

        // ---- decode, cross-half merge, write ----
#pragma unroll
        for (int pt = 0; pt < PT; ++pt) {
            unsigned leaf = 31u - (b1p[pt] & 31u);
            float m1 = __uint_as_float(b1p[pt] & 0xFFFFFFE0u);   // biased; bias cancels
            float m2 = __uint_as_float(b2p[pt] & 0xFFFFFFE0u);
            int r = (int)(leaf & 15u), ct = (int)(leaf >> 4);
            int row = (r & 3) + 8 * (r >> 2) + 4 * kh;
            int code = bchunk[pt] * CHUNK + ct * 32 + row;

            float om1 = __shfl_xor(m1, 32);
            float om2 = __shfl_xor(m2, 32);
            int   oc  = __shfl_xor(code, 32);
            bool take = (om1 > m1) || (om1 == m1 && oc < code);
            float nm2 = fmaxf(fminf(m1, om1), fmaxf(m2, om2));
            if (take) { m1 = om1; code = oc; }
            m2 = nm2;

            if (lane < 32) {
                int point = n0 + w * 64 + pt * 32 + col;
                out[point * NBOOK + b] = code;
                if (m1 - m2 < EPS_ACC) {
                    int pos = atomicAdd(counter, 1);
                    if (pos < WL_CAP) worklist[pos] = point * NBOOK + b;
                }
            }
        }
    }
}

// ---------------- fallback: exact fp32 recompute for small-margin items ----------------
__global__ __launch_bounds__(256)
void exact_kernel(const float* __restrict__ x,
                  const float* __restrict__ cb,
                  const float* __restrict__ csq,
                  const int* __restrict__ counter,
                  const int* __restrict__ worklist,
                  int* __restrict__ out) {
    __shared__ float xs[DIM];
    __shared__ float rbest[4];
    __shared__ int   ribest[4];

    int nitems = *counter;
    if (nitems > WL_CAP) nitems = WL_CAP;

    for (int item = blockIdx.x; item < nitems; item += gridDim.x) {
        int nb = worklist[item];
        int n = nb >> 2, b = nb & 3;
        __syncthreads();
        if (threadIdx.x < 32) {
            float4 v = ((const float4*)(x + (size_t)n * DIM))[threadIdx.x];
            *(float4*)&xs[threadIdx.x * 4] = v;
        }
        __syncthreads();

        const float* cbb = cb + (size_t)b * KCODES * DIM;
        const float* crow[4];
#pragma unroll
        for (int kk = 0; kk < 4; ++kk)
            crow[kk] = cbb + (size_t)(kk * 256 + threadIdx.x) * DIM;

        float dots[4] = {0.f, 0.f, 0.f, 0.f};
#pragma unroll 8
        for (int d = 0; d < DIM; d += 4) {
            float4 xv = *(const float4*)&xs[d];
#pragma unroll
            for (int kk = 0; kk < 4; ++kk) {
                float4 cv = *(const float4*)(crow[kk] + d);
                dots[kk] += xv.x * cv.x + xv.y * cv.y + xv.z * cv.z + xv.w * cv.w;
            }
        }

        float bd = 3.4e38f;
        int   bi = 0;
#pragma unroll
        for (int kk = 0; kk < 4; ++kk) {
            int k = kk * 256 + threadIdx.x;
            float dist = csq[b * KCODES + k] - 2.f * dots[kk];
            if (dist < bd) { bd = dist; bi = k; }
        }
        for (int off = 1; off < 64; off <<= 1) {
            float od = __shfl_xor(bd, off);
            int   oi = __shfl_xor(bi, off);
            if (od < bd || (od == bd && oi < bi)) { bd = od; bi = oi; }
        }
        int w = threadIdx.x >> 6;
        if ((threadIdx.x & 63) == 0) { rbest[w] = bd; ribest[w] = bi; }
        __syncthreads();
        if (threadIdx.x == 0) {
            float fb = rbest[0]; int fi = ribest[0];
            for (int i = 1; i < 4; ++i) {
                if (rbest[i] < fb || (rbest[i] == fb && ribest[i] < fi)) {
                    fb = rbest[i]; fi = ribest[i];
                }
            }
            out[nb] = fi;
        }
    }
}

extern "C" void kernel_launch(void* const* d_in, const int* in_sizes, int n_in,
                              void* d_out, int out_size, void* d_ws, size_t ws_size,
                              hipStream_t stream) {
    const float* x  = (const float*)d_in[0];   // [N, D] fp32
    const float* cb = (const float*)d_in[1];   // [B, K, D] fp32
    int* out = (int*)d_out;                    // [N, B] int32

    char* ws = (char*)d_ws;
    u16*   cbf      = (u16*)ws;
    float* csq      = (float*)(ws + WS_CSQ_OFF);
    int*   counter  = (int*)(ws + WS_CNT_OFF);
    int*   worklist = (int*)(ws + WS_WL_OFF);

    prep_kernel<<<560, 256, 0, stream>>>(cb, cbf, csq, counter);

    argmin_mfma_kernel<<<dim3(N_PTS / BPTS, 2), 256, 0, stream>>>(x, cbf, out, counter, worklist);

    exact_kernel<<<512, 256, 0, stream>>>(x, cb, csq, counter, worklist, out);
}

// Round 6
// 439.974 us; speedup vs baseline: 4.8385x; 1.0404x over previous
//
#include <hip/hip_runtime.h>
#include <math.h>

#define N_PTS  131072
#define DIM    128
#define NBOOK  4
#define KCODES 1024

#define CHUNK   32                   // codes per LDS chunk
#define NCHB    32                   // chunks per book
#define PT      2                    // point tiles (32 pts each) per wave -> 64 pts/wave
#define BPTS    256                  // 4 waves * 64 points
#define SLOTS   17                   // 8 s * 2 hl + 1 csq
#define CHUNK_BYTES (SLOTS * 1024)   // 17408 B
#define CHUNK_U16   (SLOTS * 512)    // 8704
#define EPS_ACC 2.5e-3f              // margin in acc units (~5e-3 in distance units)
#define WL_CAP  131072

typedef short  bf16x8 __attribute__((ext_vector_type(8)));
typedef float  f32x16 __attribute__((ext_vector_type(16)));
typedef unsigned short u16;

// ws layout: cbf (4*32*17408 = 2228224 B) | csq fp32[4096] | counter | worklist
#define WS_CSQ_OFF  2359296u
#define WS_CNT_OFF  (WS_CSQ_OFF + 16384u)
#define WS_WL_OFF   (WS_CNT_OFF + 256u)

__device__ inline u16 bf16_rne(float v) {
    unsigned u = __float_as_uint(v);
    return (u16)((u + 0x7fffu + ((u >> 16) & 1u)) >> 16);
}
__device__ inline float bf16_up(u16 h) { return __uint_as_float(((unsigned)h) << 16); }

__device__ inline void split2(float v, u16& hb, u16& lb) {
    hb = bf16_rne(v);
    lb = bf16_rne(v - bf16_up(hb));
}

__device__ inline void async_copy16(const void* g, void* l) {
    __builtin_amdgcn_global_load_lds(
        (const __attribute__((address_space(1))) void*)g,
        (__attribute__((address_space(3))) void*)l,
        16, 0, 0);
}

// ---------------- prep: codebook -> A-fragment bf16 (32x32x16) + csq + counter ----------
// cbf: [b][chunk(32)][slot(17)][lane(64)][8 bf16]; slot = s*2+h (s<8), 16 = csq
// A-frag: row(code-in-chunk) = lane&31, k = (lane>>5)*8 + j
// csq slot: lanes<32: k0=csq_hi,k1=csq_mid,k2=csq_r2 (x -0.5), k3=320 (x 1.0 bias)
__global__ __launch_bounds__(256)
void prep_kernel(const float* __restrict__ cb, u16* __restrict__ cbf,
                 float* __restrict__ csq, int* __restrict__ counter) {
    if (blockIdx.x >= 544) {                       // csq + counter blocks
        int idx = (blockIdx.x - 544) * 256 + threadIdx.x;   // 0..4095
        if (idx == 0) *counter = 0;
        const float4* p = (const float4*)(cb + (size_t)idx * DIM);
        float s = 0.f;
#pragma unroll
        for (int i = 0; i < DIM / 4; ++i) {
            float4 v = p[i];
            s += v.x * v.x + v.y * v.y + v.z * v.z + v.w * v.w;
        }
        csq[idx] = s;
        return;
    }
    int t    = blockIdx.x * 256 + threadIdx.x;     // 0 .. 139263
    int lane = t & 63;
    int slotIdx = t >> 6;
    int slot  = slotIdx % SLOTS;
    int bc    = slotIdx / SLOTS;                   // 0..127
    int chunk = bc & 31;
    int b     = bc >> 5;

    u16 o[8] = {0, 0, 0, 0, 0, 0, 0, 0};
    if (slot < 16) {
        int s = slot >> 1, h = slot & 1;
        int code = chunk * CHUNK + (lane & 31);
        int d0   = s * 16 + (lane >> 5) * 8;
        const float* row = cb + ((size_t)b * KCODES + code) * DIM + d0;
        float4 v0 = *(const float4*)row;
        float4 v1 = *(const float4*)(row + 4);
        float vals[8] = {v0.x, v0.y, v0.z, v0.w, v1.x, v1.y, v1.z, v1.w};
#pragma unroll
        for (int j = 0; j < 8; ++j) {
            u16 hb, lb;
            split2(vals[j], hb, lb);
            o[j] = h ? lb : hb;
        }
    } else if (lane < 32) {                        // csq slice
        int code = chunk * CHUNK + lane;
        const float4* p = (const float4*)(cb + ((size_t)b * KCODES + code) * DIM);
        float ssum = 0.f;
#pragma unroll
        for (int i = 0; i < DIM / 4; ++i) {
            float4 v = p[i];
            ssum += v.x * v.x + v.y * v.y + v.z * v.z + v.w * v.w;
        }
        u16 hb = bf16_rne(ssum);
        float rem1 = ssum - bf16_up(hb);
        u16 mb = bf16_rne(rem1);
        u16 rb = bf16_rne(rem1 - bf16_up(mb));
        o[0] = hb; o[1] = mb; o[2] = rb;
        o[3] = (u16)0x43A0;                        // 320.0 bias (x 1.0 in B)
    }
    u16* dst = cbf + (size_t)t * 8;
#pragma unroll
    for (int j = 0; j < 8; ++j) dst[j] = o[j];
}

// ---------------- main: dbuf LDS + dbuf acc, deferred epilogue -------------------------
// grid (512, 2): block y handles books {2y, 2y+1} as one 64-chunk stream
__global__ __launch_bounds__(256, 2)
void argmin_mfma_kernel(const float* __restrict__ x,
                        const u16*  __restrict__ cbf,
                        int* __restrict__ out,
                        int* __restrict__ counter,
                        int* __restrict__ worklist) {
    __shared__ u16 lds[2 * CHUNK_U16];             // 34816 B (two 17.4 KB buffers)

    const int tid  = threadIdx.x;
    const int lane = tid & 63;
    const int w    = tid >> 6;
    const int n0   = blockIdx.x * BPTS;
    const int col  = lane & 31;
    const int kh   = lane >> 5;

    const char* src0 = (const char*)cbf + (size_t)(blockIdx.y * 64) * CHUNK_BYTES;

    auto issue = [&](int c) {                      // stage chunk c -> buf[c&1]
        const char* src = src0 + (size_t)c * CHUNK_BYTES;
        char* dst = (char*)&lds[(c & 1) * CHUNK_U16];
#pragma unroll
        for (int i = 0; i < 4; ++i)
            async_copy16(src + i * 4096 + tid * 16, dst + i * 4096 + w * 1024);
        if (w == 0)
            async_copy16(src + 16384 + lane * 16, dst + 16384);
    };

    issue(0);                                      // chunk 0 in flight during x-split

    // ---- B fragments (points), hi+lo, in regs (overlaps chunk-0 staging) ----
    bf16x8 xh[PT][8], xl[PT][8];
#pragma unroll
    for (int pt = 0; pt < PT; ++pt) {
        const float* xrow = x + (size_t)(n0 + w * 64 + pt * 32 + col) * DIM;
#pragma unroll
        for (int s = 0; s < 8; ++s) {
            const float* p = xrow + s * 16 + kh * 8;
            float4 v0 = *(const float4*)p;
            float4 v1 = *(const float4*)(p + 4);
            float vals[8] = {v0.x, v0.y, v0.z, v0.w, v1.x, v1.y, v1.z, v1.w};
            bf16x8 hv, lv;
#pragma unroll
            for (int j = 0; j < 8; ++j) {
                u16 hb, lb;
                split2(vals[j], hb, lb);
                hv[j] = (short)hb;
                lv[j] = (short)lb;
            }
            xh[pt][s] = hv;
            xl[pt][s] = lv;
        }
    }
    bf16x8 xcf;                                    // csq-slice B frag
#pragma unroll
    for (int j = 0; j < 8; ++j) {
        short v = 0;
        if (kh == 0) {
            if (j < 3) v = (short)0xBF00;          // -0.5
            else if (j == 3) v = (short)0x3F80;    // 1.0
        }
        xcf[j] = v;
    }

    unsigned b1p[PT], b2p[PT];
    int bchunk[PT];
#pragma unroll
    for (int pt = 0; pt < PT; ++pt) { b1p[pt] = 0u; b2p[pt] = 0u; bchunk[pt] = 0; }

    auto mfma_chunk = [&](const u16* A, f32x16* ac) {
#pragma unroll
        for (int pt = 0; pt < PT; ++pt)
#pragma unroll
            for (int r = 0; r < 16; ++r) ac[pt][r] = 0.f;
#pragma unroll
        for (int s = 0; s < 8; ++s) {
            bf16x8 ahh = *(const bf16x8*)&A[(s * 2) * 512 + lane * 8];
            bf16x8 alo = *(const bf16x8*)&A[(s * 2 + 1) * 512 + lane * 8];
#pragma unroll
            for (int pt = 0; pt < PT; ++pt) {
                ac[pt] = __builtin_amdgcn_mfma_f32_32x32x16_bf16(ahh, xh[pt][s], ac[pt], 0, 0, 0);
                ac[pt] = __builtin_amdgcn_mfma_f32_32x32x16_bf16(ahh, xl[pt][s], ac[pt], 0, 0, 0);
                ac[pt] = __builtin_amdgcn_mfma_f32_32x32x16_bf16(alo, xh[pt][s], ac[pt], 0, 0, 0);
            }
        }
        bf16x8 acs = *(const bf16x8*)&A[16 * 512 + lane * 8];
#pragma unroll
        for (int pt = 0; pt < PT; ++pt)                 // acc = dot - csq/2 + 320
            ac[pt] = __builtin_amdgcn_mfma_f32_32x32x16_bf16(acs, xcf, ac[pt], 0, 0, 0);
    };

    auto epilogue = [&](const f32x16* ac, int cc) {     // packed top-2, larger = nearer
        int ci = cc & 31;
#pragma unroll
        for (int pt = 0; pt < PT; ++pt) {
            unsigned prev = b1p[pt], p1 = prev, p2 = b2p[pt];
#pragma unroll
            for (int r = 0; r < 16; r += 2) {
                unsigned pa = (__float_as_uint(ac[pt][r])     & 0xFFFFFFE0u) | (31u - (unsigned)r);
                unsigned pb = (__float_as_uint(ac[pt][r + 1]) & 0xFFFFFFE0u) | (30u - (unsigned)r);
                unsigned hi = pa > pb ? pa : pb;
                unsigned lo = pa < pb ? pa : pb;
                unsigned t2 = hi < p1 ? hi : p1;
                unsigned m  = lo > t2 ? lo : t2;
                p2 = p2 > m ? p2 : m;                   // -> v_max3
                p1 = p1 > hi ? p1 : hi;
            }
            bchunk[pt] = (p1 != prev) ? ci : bchunk[pt];
            b1p[pt] = p1; b2p[pt] = p2;
        }
    };

    auto finalize = [&](int book) {
        int b = blockIdx.y * 2 + book;
#pragma unroll
        for (int pt = 0; pt < PT; ++pt) {
            unsigned r = 31u - (b1p[pt] & 31u);         // leaf 0..15
            float m1 = __uint_as_float(b1p[pt] & 0xFFFFFFE0u);
            float m2 = __uint_as_float(b2p[pt] & 0xFFFFFFE0u);
            int row = (int)((r & 3u) + 8u * (r >> 2)) + 4 * kh;
            int code = bchunk[pt] * CHUNK + row;
            float om1 = __shfl_xor(m1, 32);
            float om2 = __shfl_xor(m2, 32);
            int   oc  = __shfl_xor(code, 32);
            bool take = (om1 > m1) || (om1 == m1 && oc < code);
            float nm2 = fmaxf(fminf(m1, om1), fmaxf(m2, om2));
            if (take) { m1 = om1; code = oc; }
            m2 = nm2;
            if (lane < 32) {
                int point = n0 + w * 64 + pt * 32 + col;
                out[point * NBOOK + b] = code;
                if (m1 - m2 < EPS_ACC) {
                    int pos = atomicAdd(counter, 1);
                    if (pos < WL_CAP) worklist[pos] = point * NBOOK + b;
                }
            }
            b1p[pt] = 0u; b2p[pt] = 0u; bchunk[pt] = 0;
        }
    };

    __syncthreads();                               // chunk 0 visible

    f32x16 acc0[PT], acc1[PT];
    for (int c = 0; c < 64; c += 2) {
        // ---- even chunk: buf0/acc0; epilogue of odd chunk c-1 deferred here ----
        issue(c + 1);
        mfma_chunk(lds, acc0);
        if (c > 0) {
            epilogue(acc1, c - 1);
            if (c == 32) finalize(0);              // after chunk31 epilogue
        }
        __syncthreads();                           // loads c+1 done; buf0 reads done

        // ---- odd chunk: buf1/acc1; epilogue of even chunk c deferred here ----
        if (c + 2 < 64) issue(c + 2);
        mfma_chunk(lds + CHUNK_U16, acc1);
        epilogue(acc0, c);
        __syncthreads();                           // loads c+2 done; buf1 reads done
    }
    epilogue(acc1, 63);
    finalize(1);
}

// ---------------- fallback: exact fp32 recompute for small-margin items ----------------
__global__ __launch_bounds__(256)
void exact_kernel(const float* __restrict__ x,
                  const float* __restrict__ cb,
                  const float* __restrict__ csq,
                  const int* __restrict__ counter,
                  const int* __restrict__ worklist,
                  int* __restrict__ out) {
    __shared__ float xs[DIM];
    __shared__ float rbest[4];
    __shared__ int   ribest[4];

    int nitems = *counter;
    if (nitems > WL_CAP) nitems = WL_CAP;

    for (int item = blockIdx.x; item < nitems; item += gridDim.x) {
        int nb = worklist[item];
        int n = nb >> 2, b = nb & 3;
        __syncthreads();
        if (threadIdx.x < 32) {
            float4 v = ((const float4*)(x + (size_t)n * DIM))[threadIdx.x];
            *(float4*)&xs[threadIdx.x * 4] = v;
        }
        __syncthreads();

        const float* cbb = cb + (size_t)b * KCODES * DIM;
        const float* crow[4];
#pragma unroll
        for (int kk = 0; kk < 4; ++kk)
            crow[kk] = cbb + (size_t)(kk * 256 + threadIdx.x) * DIM;

        float dots[4] = {0.f, 0.f, 0.f, 0.f};
#pragma unroll 8
        for (int d = 0; d < DIM; d += 4) {
            float4 xv = *(const float4*)&xs[d];
#pragma unroll
            for (int kk = 0; kk < 4; ++kk) {
                float4 cv = *(const float4*)(crow[kk] + d);
                dots[kk] += xv.x * cv.x + xv.y * cv.y + xv.z * cv.z + xv.w * cv.w;
            }
        }

        float bd = 3.4e38f;
        int   bi = 0;
#pragma unroll
        for (int kk = 0; kk < 4; ++kk) {
            int k = kk * 256 + threadIdx.x;
            float dist = csq[b * KCODES + k] - 2.f * dots[kk];
            if (dist < bd) { bd = dist; bi = k; }
        }
        for (int off = 1; off < 64; off <<= 1) {
            float od = __shfl_xor(bd, off);
            int   oi = __shfl_xor(bi, off);
            if (od < bd || (od == bd && oi < bi)) { bd = od; bi = oi; }
        }
        int w = threadIdx.x >> 6;
        if ((threadIdx.x & 63) == 0) { rbest[w] = bd; ribest[w] = bi; }
        __syncthreads();
        if (threadIdx.x == 0) {
            float fb = rbest[0]; int fi = ribest[0];
            for (int i = 1; i < 4; ++i) {
                if (rbest[i] < fb || (rbest[i] == fb && ribest[i] < fi)) {
                    fb = rbest[i]; fi = ribest[i];
                }
            }
            out[nb] = fi;
        }
    }
}

extern "C" void kernel_launch(void* const* d_in, const int* in_sizes, int n_in,
                              void* d_out, int out_size, void* d_ws, size_t ws_size,
                              hipStream_t stream) {
    const float* x  = (const float*)d_in[0];   // [N, D] fp32
    const float* cb = (const float*)d_in[1];   // [B, K, D] fp32
    int* out = (int*)d_out;                    // [N, B] int32

    char* ws = (char*)d_ws;
    u16*   cbf      = (u16*)ws;
    float* csq      = (float*)(ws + WS_CSQ_OFF);
    int*   counter  = (int*)(ws + WS_CNT_OFF);
    int*   worklist = (int*)(ws + WS_WL_OFF);

    prep_kernel<<<560, 256, 0, stream>>>(cb, cbf, csq, counter);

    argmin_mfma_kernel<<<dim3(N_PTS / BPTS, 2), 256, 0, stream>>>(x, cbf, out, counter, worklist);

    exact_kernel<<<1024, 256, 0, stream>>>(x, cb, csq, counter, worklist, out);
}